// Round 27
// baseline (13.753 us; speedup 1.0000x reference)
//
#include <hip/hip_runtime.h>
#include <hip/hip_fp16.h>

// GSplat renderer as a bf16 MFMA GEMM — R27 = R26 (13.54us) + vectorized
// finalize: __half2 loads (2 px/thread, 256B/wave-inst) + float2 stores.
// Gemm kernel byte-identical to R26 (recurrence staging, fast-tanh, dbuf).
// Geometry: KSPLIT=8, KCH=128x2, grid (16,4,8)=512 blocks, LDS 69 KB
// (2 blocks/CU), fp16 partials (4 MB).

constexpr int PIX = 65536;
constexpr int KB = 256;      // gaussians per block (2 chunks of 128)
constexpr int KCH = 128;     // per staging chunk
constexpr int KSPLIT = 8;
constexpr int MT = 64;
constexpr int NT = 64;
constexpr float COORD_STEP = 2.0f / 255.0f;
constexpr float TWO_S = 2.0f * COORD_STEP;
constexpr float S_SQ = COORD_STEP * COORD_STEP;

typedef __attribute__((ext_vector_type(8))) short short8;
typedef __attribute__((ext_vector_type(4))) float f32x4;

__device__ __forceinline__ unsigned cvt_pk_bf16(float lo, float hi) {
  unsigned r;
  asm("v_cvt_pk_bf16_f32 %0, %1, %2" : "=v"(r) : "v"(lo), "v"(hi));
  return r;
}
__device__ __forceinline__ float ex2(float x) {
  return __builtin_amdgcn_exp2f(x);   // bare v_exp_f32
}
__device__ __forceinline__ float rcp_(float x) {
  return __builtin_amdgcn_rcpf(x);    // v_rcp_f32, 1 ulp
}
__device__ __forceinline__ float tanh_fast(float x) {
  float t = ex2(2.885390082f * x);    // e^{2x}
  return fmaf(-2.0f, rcp_(t + 1.0f), 1.0f);
}

__global__ __launch_bounds__(256) void gs_mfma(
    const float* __restrict__ means, const float* __restrict__ scales,
    const float* __restrict__ opac, const float* __restrict__ colors,
    __half* __restrict__ partials) {
  __shared__ unsigned short A_l[2][MT * KCH];  // 2 x 16 KB, swizzled
  __shared__ unsigned short B_l[2][NT * KCH];  // 2 x 16 KB, swizzled
  __shared__ float pxL[KB], pyL[KB], kKL[KB], colL[KB], qL[KB];  // 5 KB

  const int t = threadIdx.x;
  const int mt = blockIdx.x;          // 0..15: c = mt>>2, rowband (mt&3)*64
  const int nt = blockIdx.y;          // 0..3
  const int kp = blockIdx.z;          // 0..7
  const int c = mt >> 2;
  const int row0 = (mt & 3) * MT;
  const int col0 = nt * NT;

  // --- params for BOTH chunks (1 gaussian per thread, once) ---
  {
    int n = kp * KB + t;
    float mx = means[3 * n], my = means[3 * n + 1], mz = means[3 * n + 2];
    float scl = fmaxf((scales[3 * n] + scales[3 * n + 1] + scales[3 * n + 2]) * (1.0f / 3.0f), 1e-4f);
    float op = opac[n];
    float rzs = rcp_(fabsf(mz) + 1.0f);
    float sigma = fminf(fmaxf(scl * rzs, 0.02f), 0.5f);
    float inv_s = rcp_(sigma);
    float K = -0.72134752044f * inv_s * inv_s;  // -0.5/ln2 * inv_s^2
    pxL[t] = tanh_fast(mx * rzs);
    pyL[t] = tanh_fast(my * rzs);
    kKL[t] = K;
    qL[t] = ex2(2.0f * K * S_SQ);
    colL[t] = (c < 3) ? op * colors[3 * n + c] : op;
  }

  // MFMA lane mapping
  const int w = t >> 6;
  const int lr = t & 15;
  const int lg = (t >> 4) & 3;
  const int ra = w * 16 + lr;
  const unsigned offA = (unsigned)(ra * 256 + lg * 16);
  const unsigned swA = (unsigned)((ra & 7) << 4);
  const unsigned swB = (unsigned)((lr & 7) << 4);
  const unsigned offB0 = (unsigned)((0 * 16 + lr) * 256 + lg * 16);
  const unsigned offB1 = (unsigned)((1 * 16 + lr) * 256 + lg * 16);
  const unsigned offB2 = (unsigned)((2 * 16 + lr) * 256 + lg * 16);
  const unsigned offB3 = (unsigned)((3 * 16 + lr) * 256 + lg * 16);

  f32x4 acc0 = {0.f, 0.f, 0.f, 0.f};
  f32x4 acc1 = acc0, acc2 = acc0, acc3 = acc0;

  // staging thread mapping
  const int kq = (t & 31) << 2;       // 4 gaussians (local k)
  const int mq = (t >> 5) << 3;       // 8 rows/cols
  const int kbyte = (t & 31) << 3;

  auto STAGE = [&](unsigned short* Ab, unsigned short* Bb, int cc) {
    const int kk = cc * KCH + kq;
    const float crA0 = -1.0f + COORD_STEP * (float)(row0 + mq);
    const float ccB0 = -1.0f + COORD_STEP * (float)(col0 + mq);
    float wA[4], rA[4], wB[4], rB[4], qv[4];
#pragma unroll
    for (int i = 0; i < 4; ++i) {
      float K = kKL[kk + i];
      float py = pyL[kk + i];
      float px = pxL[kk + i];
      qv[i] = qL[kk + i];
      float dA = crA0 - py;
      wA[i] = ex2(K * dA * dA) * colL[kk + i];   // color folded in
      rA[i] = ex2(K * fmaf(TWO_S, dA, S_SQ));
      float dB = ccB0 - px;
      wB[i] = ex2(K * dB * dB);
      rB[i] = ex2(K * fmaf(TWO_S, dB, S_SQ));
    }
#pragma unroll
    for (int j = 0; j < 8; ++j) {
      int m = mq + j;
      uint2 pa, pb;
      pa.x = cvt_pk_bf16(wA[0], wA[1]);
      pa.y = cvt_pk_bf16(wA[2], wA[3]);
      pb.x = cvt_pk_bf16(wB[0], wB[1]);
      pb.y = cvt_pk_bf16(wB[2], wB[3]);
      unsigned ds = (unsigned)((m * 256 + kbyte) ^ ((m & 7) << 4));
      *(uint2*)((char*)Ab + ds) = pa;
      *(uint2*)((char*)Bb + ds) = pb;
#pragma unroll
      for (int i = 0; i < 4; ++i) {
        wA[i] *= rA[i]; rA[i] *= qv[i];
        wB[i] *= rB[i]; rB[i] *= qv[i];
      }
    }
  };

  auto MFMA_PHASE = [&](const unsigned short* Ab, const unsigned short* Bb) {
#pragma unroll
    for (int s = 0; s < 4; ++s) {
      const unsigned ks = (unsigned)(s * 64);
      short8 af = *(const short8*)((const char*)Ab + ((offA + ks) ^ swA));
      short8 b0 = *(const short8*)((const char*)Bb + ((offB0 + ks) ^ swB));
      short8 b1 = *(const short8*)((const char*)Bb + ((offB1 + ks) ^ swB));
      short8 b2 = *(const short8*)((const char*)Bb + ((offB2 + ks) ^ swB));
      short8 b3 = *(const short8*)((const char*)Bb + ((offB3 + ks) ^ swB));
      acc0 = __builtin_amdgcn_mfma_f32_16x16x32_bf16(af, b0, acc0, 0, 0, 0);
      acc1 = __builtin_amdgcn_mfma_f32_16x16x32_bf16(af, b1, acc1, 0, 0, 0);
      acc2 = __builtin_amdgcn_mfma_f32_16x16x32_bf16(af, b2, acc2, 0, 0, 0);
      acc3 = __builtin_amdgcn_mfma_f32_16x16x32_bf16(af, b3, acc3, 0, 0, 0);
    }
  };

  __syncthreads();                 // params visible
  STAGE(A_l[0], B_l[0], 0);
  __syncthreads();                 // buf0 ready
  STAGE(A_l[1], B_l[1], 1);       // || MFMA(buf0): separate pipes
  MFMA_PHASE(A_l[0], B_l[0]);
  __syncthreads();                 // buf1 ready
  MFMA_PHASE(A_l[1], B_l[1]);

  // --- epilogue: fp16 partials; D col=lane&15, row=lg*4+r (m89/m91) ---
  {
    __half* pb = partials +
        (((size_t)kp * 1024 + c * 256 + row0 + w * 16 + lg * 4) * 256) +
        col0 + lr;
#pragma unroll
    for (int r = 0; r < 4; ++r) {
      pb[r * 256 + 0]  = __float2half(acc0[r]);
      pb[r * 256 + 16] = __float2half(acc1[r]);
      pb[r * 256 + 32] = __float2half(acc2[r]);
      pb[r * 256 + 48] = __float2half(acc3[r]);
    }
  }
}

// grid = 128 blocks x 256 threads; thread = TWO adjacent pixels (half2).
__global__ __launch_bounds__(256) void gs_finalize(
    const __half2* __restrict__ partials2, float* __restrict__ out) {
  int g = blockIdx.x * 256 + threadIdx.x;   // half2-group id, 0..PIX/2-1
  float2 s0 = {0.f, 0.f}, s1 = s0, s2 = s0, s3 = s0;
#pragma unroll
  for (int kp = 0; kp < KSPLIT; ++kp) {
    const __half2* base = partials2 + (size_t)kp * 4 * (PIX / 2) + g;
    float2 a = __half22float2(base[0 * (PIX / 2)]);
    float2 b = __half22float2(base[1 * (PIX / 2)]);
    float2 cc = __half22float2(base[2 * (PIX / 2)]);
    float2 d = __half22float2(base[3 * (PIX / 2)]);
    s0.x += a.x; s0.y += a.y;
    s1.x += b.x; s1.y += b.y;
    s2.x += cc.x; s2.y += cc.y;
    s3.x += d.x; s3.y += d.y;
  }
  float ix = 1.0f / fmaxf(s3.x, 1e-5f);
  float iy = 1.0f / fmaxf(s3.y, 1e-5f);
  float2* out2 = (float2*)out;
  out2[0 * (PIX / 2) + g] = make_float2(fminf(fmaxf(s0.x * ix, 0.f), 1.f),
                                        fminf(fmaxf(s0.y * iy, 0.f), 1.f));
  out2[1 * (PIX / 2) + g] = make_float2(fminf(fmaxf(s1.x * ix, 0.f), 1.f),
                                        fminf(fmaxf(s1.y * iy, 0.f), 1.f));
  out2[2 * (PIX / 2) + g] = make_float2(fminf(fmaxf(s2.x * ix, 0.f), 1.f),
                                        fminf(fmaxf(s2.y * iy, 0.f), 1.f));
}

extern "C" void kernel_launch(void* const* d_in, const int* in_sizes, int n_in,
                              void* d_out, int out_size, void* d_ws, size_t ws_size,
                              hipStream_t stream) {
  const float* means = (const float*)d_in[0];
  // d_in[1] = quats (unused by reference)
  const float* scales = (const float*)d_in[2];
  const float* opac = (const float*)d_in[3];
  const float* colors = (const float*)d_in[4];
  float* out = (float*)d_out;

  // ws: partials [KSPLIT][1024][256] fp16 = 4 MB
  __half* partials = (__half*)d_ws;

  gs_mfma<<<dim3(16, 4, KSPLIT), 256, 0, stream>>>(
      means, scales, opac, colors, partials);
  gs_finalize<<<PIX / 2 / 256, 256, 0, stream>>>(
      (const __half2*)partials, out);
}